// Round 1
// baseline (649.251 us; speedup 1.0000x reference)
//
#include <hip/hip_runtime.h>

// SplitConvStack: 3x depthwise dilated conv1d along W + ReLU, fused.
// x: [B=16, H=21, W=4096, C=64] fp32 NHWC; w1/w2/w3: [1,8,1,64].
// Stage dilations 1,2,4; SAME padding -> pad_lo = 3, 7, 14.
//
// One wave (64 lanes = 64 channels) streams one chunk of 256 W-positions of
// one (b,h) row through a register software pipeline:
//   step t: load x[t+8] -> xf ; s1[t-4] from xf ; s2[t-11] from s1f ;
//           s3[t-25] from s2f -> store.
// FIFO sizes 16/16/32 divide the 32-step unrolled group and chunk bases are
// multiples of 32, so every FIFO index is a compile-time constant (pure
// register renaming; no LDS, no shifts).

#define W_DIM   4096
#define C_DIM   64
#define L_CHUNK 256
#define NCHUNK  16      // W / L_CHUNK
#define NROWS   336     // B*H = 16*21
#define WAVES_PER_BLOCK 4

__global__ __launch_bounds__(256, 4)
void splitconv_fused_kernel(const float* __restrict__ x,
                            const float* __restrict__ w1,
                            const float* __restrict__ w2,
                            const float* __restrict__ w3,
                            float* __restrict__ out) {
    const int lane   = threadIdx.x & 63;              // channel
    const int waveId = blockIdx.x * WAVES_PER_BLOCK + (threadIdx.x >> 6);
    const int row    = waveId >> 4;                   // [0, 336)
    const int chunk  = waveId & (NCHUNK - 1);
    const int w0     = chunk * L_CHUNK;               // multiple of 256
    const int c      = lane;

    const float* __restrict__ xrow = x   + (size_t)row * (W_DIM * C_DIM) + c;
    float* __restrict__       orow = out + (size_t)row * (W_DIM * C_DIM) + c;

    // per-lane weights: w[k*C + c]
    float w1r[8], w2r[8], w3r[8];
#pragma unroll
    for (int k = 0; k < 8; ++k) {
        w1r[k] = w1[k * C_DIM + c];
        w2r[k] = w2[k * C_DIM + c];
        w3r[k] = w3[k * C_DIM + c];
    }

    float xf[16], s1f[16], s2f[32];
#pragma unroll
    for (int i = 0; i < 16; ++i) { xf[i] = 0.f; s1f[i] = 0.f; }
#pragma unroll
    for (int i = 0; i < 32; ++i) s2f[i] = 0.f;

    // pipeline: t in [w0-32, w0+288), 10 groups of 32 steps
    for (int g = 0; g < 10; ++g) {
        const int tbase = w0 - 32 + g * 32;           // == 0 (mod 32)
#pragma unroll
        for (int j = 0; j < 32; ++j) {
            const int t = tbase + j;                  // t == j (mod 32)

            // ---- prefetch x[t+8] into xf[(t+8) % 16] ----
            {
                const int z = t + 8;
                float xv = 0.f;
                if (z >= 0 && z < W_DIM && (z - w0) <= L_CHUNK + 24)
                    xv = xrow[(size_t)z * C_DIM];
                xf[(j + 8) & 15] = xv;
            }

            // ---- stage 1 (d=1, pad_lo=3): s1[v], v = t-4, taps x[v-3..v+4] ----
            {
                const int v = t - 4;
                float a = 0.f;
#pragma unroll
                for (int k = 0; k < 8; ++k)
                    a = fmaf(xf[(j - 7 + k + 32) & 15], w1r[k], a);
                float s = fmaxf(a, 0.f);
                s1f[(j - 4 + 32) & 15] = (v >= 0 && v < W_DIM) ? s : 0.f;
            }

            // ---- stage 2 (d=2, pad_lo=7): s2[u], u = t-11, taps s1[u-7+2k] ----
            {
                const int u = t - 11;
                float a = 0.f;
#pragma unroll
                for (int k = 0; k < 8; ++k)
                    a = fmaf(s1f[(j - 18 + 2 * k + 32) & 15], w2r[k], a);
                float s = fmaxf(a, 0.f);
                s2f[(j - 11 + 32) & 31] = (u >= 0 && u < W_DIM) ? s : 0.f;
            }

            // ---- stage 3 (d=4, pad_lo=14): y[wq], wq = t-25, taps s2[wq-14+4k] ----
            {
                const int wq = t - 25;
                if (wq >= w0 && wq < w0 + L_CHUNK) {
                    float a = 0.f;
#pragma unroll
                    for (int k = 0; k < 8; ++k)
                        a = fmaf(s2f[(j - 39 + 4 * k + 64) & 31], w3r[k], a);
                    orow[(size_t)wq * C_DIM] = fmaxf(a, 0.f);
                }
            }
        }
    }
}

extern "C" void kernel_launch(void* const* d_in, const int* in_sizes, int n_in,
                              void* d_out, int out_size, void* d_ws, size_t ws_size,
                              hipStream_t stream) {
    const float* x  = (const float*)d_in[0];
    const float* w1 = (const float*)d_in[1];
    const float* w2 = (const float*)d_in[2];
    const float* w3 = (const float*)d_in[3];
    float* out = (float*)d_out;

    const int totalWaves = NROWS * NCHUNK;                 // 5376
    const int blocks = totalWaves / WAVES_PER_BLOCK;       // 1344
    splitconv_fused_kernel<<<blocks, 256, 0, stream>>>(x, w1, w2, w3, out);
}